// Round 3
// baseline (509.015 us; speedup 1.0000x reference)
//
#include <hip/hip_runtime.h>
#include <stdint.h>

#define S 2048
#define HID 3584
#define NH 16
#define NKV 8
#define DH 256
#define WINDOW 1024
#define SCALE 0.0625f
#define CAP 50.0f

typedef short s16x8 __attribute__((ext_vector_type(8)));
typedef float f32x4 __attribute__((ext_vector_type(4)));

__device__ __forceinline__ short f2bf(float f) {
  union { float f; uint32_t u; } c; c.f = f;
  uint32_t u = c.u;
  uint32_t r = (u + 0x7FFFu + ((u >> 16) & 1u)) >> 16;
  return (short)r;
}
__device__ __forceinline__ float bf2f(short s) {
  union { uint32_t u; float f; } c;
  c.u = ((uint32_t)(uint16_t)s) << 16;
  return c.f;
}
__device__ __forceinline__ void gll16(const void* g, void* l) {
  __builtin_amdgcn_global_load_lds((const __attribute__((address_space(1))) void*)g,
                                   (__attribute__((address_space(3))) void*)l, 16, 0, 0);
}

// ---------------- RoPE table ----------------
__global__ void rope_table_kernel(float2* __restrict__ tbl) {
  int idx = blockIdx.x * 256 + threadIdx.x;
  int s = idx >> 7, i = idx & 127;
  float inv = __expf(-(float)i * (9.210340371976184f / 128.0f));
  float fr = (float)s * inv;
  tbl[idx] = make_float2(cosf(fr), sinf(fr));
}

// ---------------- hs fp32 -> bf16 ----------------
__global__ void conv_hs_kernel(const float* __restrict__ src, short* __restrict__ dst) {
  int gid = blockIdx.x * 256 + threadIdx.x;
  float4 a = *(const float4*)&src[(size_t)gid * 8];
  float4 b = *(const float4*)&src[(size_t)gid * 8 + 4];
  s16x8 o;
  o[0] = f2bf(a.x); o[1] = f2bf(a.y); o[2] = f2bf(a.z); o[3] = f2bf(a.w);
  o[4] = f2bf(b.x); o[5] = f2bf(b.y); o[6] = f2bf(b.z); o[7] = f2bf(b.w);
  *(s16x8*)&dst[(size_t)gid * 8] = o;
}

// ---------------- W fp32 [K][N] -> bf16 [N][K] (transpose+convert) --------
__global__ __launch_bounds__(256)
void transpose_kernel(const float* __restrict__ src, short* __restrict__ dst,
                      int K, int N)
{
  __shared__ __align__(16) short t[64][76];
  int ntn = N >> 6;
  int tn = blockIdx.x % ntn, tk = blockIdx.x / ntn;
  int tid = threadIdx.x;
  int c = tid & 63, rg = tid >> 6;
  #pragma unroll
  for (int i = 0; i < 4; ++i) {
    int r0 = i * 16 + rg * 4;
    short tmp[4];
    #pragma unroll
    for (int j = 0; j < 4; ++j)
      tmp[j] = f2bf(src[(size_t)(tk * 64 + r0 + j) * N + tn * 64 + c]);
    *(short4*)&t[c][r0] = *(short4*)tmp;
  }
  __syncthreads();
  #pragma unroll
  for (int it = 0; it < 2; ++it) {
    int flat = it * 256 + tid;
    int n = flat >> 3, kc = flat & 7;
    *(s16x8*)&dst[(size_t)(tn * 64 + n) * K + tk * 64 + kc * 8] = *(s16x8*)&t[n][kc * 8];
  }
}

// =========== 8-phase 256xBN GEMM core (T2+T3+T4+T5), BK=64, 512 thr ========
// A: [256][64] bf16 per buffer, B: [BN][64] (n-major). XOR-swizzle
// col_bytes ^= (row&7)<<4 on both stage-source and frag-read sides.
template<int BN, int KS>
__device__ __forceinline__ void gemm8_core(const short* __restrict__ srcA,
                                           const short* __restrict__ srcB,
                                           int tid, int NT,
                                           f32x4 (&acc)[8][BN / 64])
{
  constexpr int NF  = BN / 64;     // n-frags per wave (4 or 2)
  constexpr int NFP = NF / 2;      // n-frags per phase (2 or 1)
  constexpr int BSI = BN / 64;     // B stage instructions per tile (4 or 2)
  constexpr int WC  = BN / 4;      // per-wave cols
  __shared__ __align__(16) short Asb[2 * 16384];
  __shared__ __align__(16) short Bsb[2 * BN * 64];
  const int wv = tid >> 6, lane = tid & 63;
  const int lr = lane & 15, lk = lane >> 4;
  const int wm_id = wv >> 2, wn_id = wv & 3;
  const int r7 = lr & 7;
  const int abase = (wm_id * 128 + lr) * 64 + ((lk ^ r7) * 8);
  const int bbase = (wn_id * WC + lr) * 64 + ((lk ^ r7) * 8);

  auto stage = [&](int kt, int b) {
    const short* sa = srcA + kt * 64;
    const short* sb = srcB + kt * 64;
    short* la = Asb + b * 16384 + wv * 512;
    short* lb = Bsb + b * BN * 64 + wv * 512;
    #pragma unroll
    for (int i = 0; i < 4; ++i)
      gll16(sa + (size_t)i * 64 * KS, la + i * 4096);
    #pragma unroll
    for (int i = 0; i < BSI; ++i)
      gll16(sb + (size_t)i * 64 * KS, lb + i * 4096);
  };

  stage(0, 0);
  stage(1, 1);
  if constexpr (BN == 256) asm volatile("s_waitcnt vmcnt(8)" ::: "memory");
  else                     asm volatile("s_waitcnt vmcnt(6)" ::: "memory");
  asm volatile("s_barrier" ::: "memory");

  for (int t = 0; t < NT; ++t) {
    const int cur = t & 1;
    const short* A = Asb + cur * 16384;
    const short* B = Bsb + cur * BN * 64;
    #pragma unroll
    for (int mh = 0; mh < 2; ++mh)
      #pragma unroll
      for (int nh = 0; nh < 2; ++nh) {
        s16x8 af[4][2], bfr[NFP][2];
        #pragma unroll
        for (int mf = 0; mf < 4; ++mf)
          #pragma unroll
          for (int kh = 0; kh < 2; ++kh)
            af[mf][kh] = *(const s16x8*)&A[(abase + (mh * 64 + mf * 16) * 64) ^ (kh * 32)];
        #pragma unroll
        for (int nf = 0; nf < NFP; ++nf)
          #pragma unroll
          for (int kh = 0; kh < 2; ++kh)
            bfr[nf][kh] = *(const s16x8*)&B[(bbase + (nh * NFP + nf) * 16 * 64) ^ (kh * 32)];
        asm volatile("s_barrier" ::: "memory");
        asm volatile("s_waitcnt lgkmcnt(0)" ::: "memory");
        __builtin_amdgcn_s_setprio(1);
        #pragma unroll
        for (int mf = 0; mf < 4; ++mf)
          #pragma unroll
          for (int nf = 0; nf < NFP; ++nf) {
            acc[mh * 4 + mf][nh * NFP + nf] =
              __builtin_amdgcn_mfma_f32_16x16x32_bf16(af[mf][0], bfr[nf][0],
                                                      acc[mh * 4 + mf][nh * NFP + nf], 0, 0, 0);
            acc[mh * 4 + mf][nh * NFP + nf] =
              __builtin_amdgcn_mfma_f32_16x16x32_bf16(af[mf][1], bfr[nf][1],
                                                      acc[mh * 4 + mf][nh * NFP + nf], 0, 0, 0);
          }
        __builtin_amdgcn_s_setprio(0);
        asm volatile("s_barrier" ::: "memory");
      }
    if (t + 2 < NT) {
      stage(t + 2, cur);
      if constexpr (BN == 256) asm volatile("s_waitcnt vmcnt(8)" ::: "memory");
      else                     asm volatile("s_waitcnt vmcnt(6)" ::: "memory");
      asm volatile("s_barrier" ::: "memory");
    } else if (t + 1 < NT) {
      asm volatile("s_waitcnt vmcnt(0)" ::: "memory");
      asm volatile("s_barrier" ::: "memory");
    }
  }
}

// ---------------- Fused QKV GEMM (8-phase 256^2) ----------------
__global__ __launch_bounds__(512, 2)
void qkv_gemm8_kernel(const short* __restrict__ hsb, const short* __restrict__ Wt,
                      short* __restrict__ qb, short* __restrict__ kbuf,
                      short* __restrict__ vtb)
{
  int bid = blockIdx.x;                      // 256 blocks = 8 bm x 32 bn
  int swz = (bid & 7) * 32 + (bid >> 3);
  int bm = swz >> 5, bn = swz & 31;
  int m0 = bm * 256, n0 = bn * 256;
  int tid = threadIdx.x;
  int row8 = tid >> 3;
  int colsw = ((tid & 7) ^ (row8 & 7)) * 8;
  const short* srcA = hsb + (size_t)(m0 + row8) * HID + colsw;
  const short* srcB = Wt + (size_t)(n0 + row8) * HID + colsw;
  f32x4 acc[8][4] = {};
  gemm8_core<256, HID>(srcA, srcB, tid, HID / 64, acc);

  int wv = tid >> 6, lane = tid & 63;
  int lr = lane & 15, lk = lane >> 4;
  int wm = (wv >> 2) * 128, wn = (wv & 3) * 64;
  int region = (n0 < 4096) ? 0 : ((n0 < 6144) ? 1 : 2);
  #pragma unroll
  for (int m = 0; m < 8; ++m) {
    int srow_b = m0 + wm + m * 16 + lk * 4;
    #pragma unroll
    for (int n = 0; n < 4; ++n) {
      int ncol = n0 + wn + n * 16 + lr;
      #pragma unroll
      for (int r = 0; r < 4; ++r) {
        int srow = srow_b + r;
        short bv = f2bf(acc[m][n][r]);
        if (region == 0) {
          int h = ncol >> 8, d = ncol & 255;
          qb[((size_t)h * S + srow) * DH + d] = bv;
        } else if (region == 1) {
          int c = ncol - 4096; int kv = c >> 8, d = c & 255;
          kbuf[((size_t)kv * S + srow) * DH + d] = bv;
        } else {
          int c = ncol - 6144; int kv = c >> 8, d = c & 255;
          vtb[((size_t)kv * DH + d) * S + srow] = bv;
        }
      }
    }
  }
}

// ---------------- Output GEMM (8-phase 256x128) ----------------
__global__ __launch_bounds__(512, 2)
void out_gemm8_kernel(const short* __restrict__ attnb, const short* __restrict__ WtO,
                      float* __restrict__ out)
{
  int bid = blockIdx.x;                      // 224 blocks = 8 bm x 28 bn
  int swz = (bid & 7) * 28 + (bid >> 3);
  int bm = swz / 28, bn = swz % 28;
  int m0 = bm * 256, n0 = bn * 128;
  int tid = threadIdx.x;
  int row8 = tid >> 3;
  int colsw = ((tid & 7) ^ (row8 & 7)) * 8;
  const short* srcA = attnb + (size_t)(m0 + row8) * 4096 + colsw;
  const short* srcB = WtO + (size_t)(n0 + row8) * 4096 + colsw;
  f32x4 acc[8][2] = {};
  gemm8_core<128, 4096>(srcA, srcB, tid, 4096 / 64, acc);

  int wv = tid >> 6, lane = tid & 63;
  int lr = lane & 15, lk = lane >> 4;
  int wm = (wv >> 2) * 128, wn = (wv & 3) * 32;
  #pragma unroll
  for (int m = 0; m < 8; ++m) {
    int srow_b = m0 + wm + m * 16 + lk * 4;
    #pragma unroll
    for (int n = 0; n < 2; ++n) {
      int ncol = n0 + wn + n * 16 + lr;
      #pragma unroll
      for (int r = 0; r < 4; ++r)
        out[(size_t)(srow_b + r) * HID + ncol] = acc[m][n][r];
    }
  }
}

// ---------------- RoPE (NeoX, in place on q and k) ----------------
__global__ void rope_kernel(short* __restrict__ qb, short* __restrict__ kbuf,
                            const float2* __restrict__ tbl)
{
  int gid = blockIdx.x * 256 + threadIdx.x;
  int row = gid >> 4, ch = gid & 15;
  short* base = (row < NH * S) ? (qb + (size_t)row * DH)
                               : (kbuf + (size_t)(row - NH * S) * DH);
  int s = row & (S - 1);
  int i0 = ch * 8;
  s16x8 x1 = *(s16x8*)(base + i0);
  s16x8 x2 = *(s16x8*)(base + 128 + i0);
  s16x8 y1, y2;
  #pragma unroll
  for (int j = 0; j < 8; ++j) {
    float2 cs = tbl[s * 128 + i0 + j];
    float a = bf2f(x1[j]), b = bf2f(x2[j]);
    y1[j] = f2bf(a * cs.x - b * cs.y);
    y2[j] = f2bf(b * cs.x + a * cs.y);
  }
  *(s16x8*)(base + i0) = y1;
  *(s16x8*)(base + 128 + i0) = y2;
}

// ---------------- Attention (flash-style, GQA, window+causal, softcap) ----
__global__ __launch_bounds__(256)
void attn_kernel(const short* __restrict__ qb, const short* __restrict__ kbuf,
                 const short* __restrict__ vtb, short* __restrict__ attnb)
{
  __shared__ __align__(16) short Klds[64][264];
  __shared__ __align__(16) short Vlds[256][72];
  __shared__ __align__(16) short Plds[4][16][72];
  int bid = blockIdx.x;
  int h = bid >> 5, qt = bid & 31;
  int kv = h >> 1;
  int q0 = qt * 64;
  int tid = threadIdx.x, w = tid >> 6, lane = tid & 63;
  int lr = lane & 15, lk = lane >> 4;
  int qrow_base = q0 + w * 16;
  s16x8 qf[8];
  const short* qrow = qb + ((size_t)h * S + (qrow_base + lr)) * DH;
  #pragma unroll
  for (int kb = 0; kb < 8; ++kb)
    qf[kb] = *(const s16x8*)(qrow + kb * 32 + lk * 8);
  f32x4 acc_o[16] = {};
  float m_r[4], l_r[4];
  #pragma unroll
  for (int r = 0; r < 4; ++r) { m_r[r] = -1e30f; l_r[r] = 0.0f; }
  int tlo = (q0 >= WINDOW - 1) ? ((q0 - (WINDOW - 1)) >> 6) : 0;
  int thi = q0 >> 6;
  const short* kbase = kbuf + (size_t)kv * S * DH;
  const short* vbase = vtb + (size_t)kv * DH * S;
  for (int t = tlo; t <= thi; ++t) {
    int k0 = t * 64;
    __syncthreads();
    #pragma unroll
    for (int it = 0; it < 8; ++it) {
      int ch = it * 256 + tid;
      int r = ch >> 5, cg = ch & 31;
      *(s16x8*)&Klds[r][cg * 8] = *(const s16x8*)(kbase + (size_t)(k0 + r) * DH + cg * 8);
    }
    #pragma unroll
    for (int it = 0; it < 8; ++it) {
      int ch = it * 256 + tid;
      int r = ch >> 3, cg = ch & 7;
      *(s16x8*)&Vlds[r][cg * 8] = *(const s16x8*)(vbase + (size_t)r * S + k0 + cg * 8);
    }
    __syncthreads();
    f32x4 sc[4] = {};
    #pragma unroll
    for (int kb = 0; kb < 8; ++kb)
      #pragma unroll
      for (int ni = 0; ni < 4; ++ni) {
        s16x8 b = *(const s16x8*)&Klds[ni * 16 + lr][kb * 32 + lk * 8];
        sc[ni] = __builtin_amdgcn_mfma_f32_16x16x32_bf16(qf[kb], b, sc[ni], 0, 0, 0);
      }
    bool validm[4][4];
    #pragma unroll
    for (int ni = 0; ni < 4; ++ni)
      #pragma unroll
      for (int r = 0; r < 4; ++r) {
        float sv = sc[ni][r] * SCALE;
        sv = CAP * tanhf(sv * (1.0f / CAP));
        int qg = qrow_base + lk * 4 + r;
        int kg = k0 + ni * 16 + lr;
        bool valid = (kg <= qg) && (qg - kg < WINDOW);
        validm[ni][r] = valid;
        sc[ni][r] = valid ? sv : -1e30f;
      }
    float alpha[4];
    #pragma unroll
    for (int r = 0; r < 4; ++r) {
      float mx = fmaxf(fmaxf(sc[0][r], sc[1][r]), fmaxf(sc[2][r], sc[3][r]));
      #pragma unroll
      for (int off = 1; off < 16; off <<= 1)
        mx = fmaxf(mx, __shfl_xor(mx, off, 64));
      float mnew = fmaxf(m_r[r], mx);
      alpha[r] = __expf(m_r[r] - mnew);
      m_r[r] = mnew;
      float sum = 0.0f;
      #pragma unroll
      for (int ni = 0; ni < 4; ++ni) {
        float p = validm[ni][r] ? __expf(sc[ni][r] - mnew) : 0.0f;
        sc[ni][r] = p;
        sum += p;
      }
      #pragma unroll
      for (int off = 1; off < 16; off <<= 1)
        sum += __shfl_xor(sum, off, 64);
      l_r[r] = l_r[r] * alpha[r] + sum;
    }
    #pragma unroll
    for (int ni = 0; ni < 4; ++ni)
      #pragma unroll
      for (int r = 0; r < 4; ++r)
        Plds[w][lk * 4 + r][ni * 16 + lr] = f2bf(sc[ni][r]);
    __syncthreads();
    #pragma unroll
    for (int df = 0; df < 16; ++df)
      #pragma unroll
      for (int r = 0; r < 4; ++r)
        acc_o[df][r] *= alpha[r];
    s16x8 pa0 = *(const s16x8*)&Plds[w][lr][lk * 8];
    s16x8 pa1 = *(const s16x8*)&Plds[w][lr][32 + lk * 8];
    #pragma unroll
    for (int df = 0; df < 16; ++df) {
      s16x8 b0 = *(const s16x8*)&Vlds[df * 16 + lr][lk * 8];
      s16x8 b1 = *(const s16x8*)&Vlds[df * 16 + lr][32 + lk * 8];
      acc_o[df] = __builtin_amdgcn_mfma_f32_16x16x32_bf16(pa0, b0, acc_o[df], 0, 0, 0);
      acc_o[df] = __builtin_amdgcn_mfma_f32_16x16x32_bf16(pa1, b1, acc_o[df], 0, 0, 0);
    }
  }
  #pragma unroll
  for (int r = 0; r < 4; ++r) {
    int srow = qrow_base + lk * 4 + r;
    float inv = 1.0f / l_r[r];
    #pragma unroll
    for (int df = 0; df < 16; ++df)
      attnb[(size_t)srow * (NH * DH) + h * DH + df * 16 + lr] = f2bf(acc_o[df][r] * inv);
  }
}

extern "C" void kernel_launch(void* const* d_in, const int* in_sizes, int n_in,
                              void* d_out, int out_size, void* d_ws, size_t ws_size,
                              hipStream_t stream) {
  const float* hs = (const float*)d_in[0];
  const float* Wq = (const float*)d_in[2];
  const float* Wk = (const float*)d_in[3];
  const float* Wv = (const float*)d_in[4];
  const float* Wo = (const float*)d_in[5];
  float* out = (float*)d_out;
  char* ws = (char*)d_ws;
  size_t off = 0;
  float2* tbl  = (float2*)(ws + off); off += 2097152;
  short* qb    = (short*)(ws + off);  off += 16777216;           // q  [H][S][D]
  short* kbuf  = (short*)(ws + off);  off += 8388608;            // k  [KV][S][D]
  short* vtb   = (short*)(ws + off);  off += 8388608;            // vT [KV][D][S]
  short* attnb = (short*)(ws + off);  off += 16777216;           // attn [S][4096]
  short* hsb   = (short*)(ws + off);  off += 14680064;           // hs bf16
  short* Wt    = (short*)(ws + off);  off += 58720256;           // [8192][3584]
  short* WtO   = (short*)(ws + off);  off += 29360128;           // [3584][4096]

  hipLaunchKernelGGL(rope_table_kernel, dim3(1024), dim3(256), 0, stream, tbl);
  hipLaunchKernelGGL(conv_hs_kernel, dim3(3584), dim3(256), 0, stream, hs, hsb);
  hipLaunchKernelGGL(transpose_kernel, dim3(64 * 56), dim3(256), 0, stream,
                     Wq, Wt, HID, 4096);
  hipLaunchKernelGGL(transpose_kernel, dim3(32 * 56), dim3(256), 0, stream,
                     Wk, Wt + (size_t)4096 * HID, HID, 2048);
  hipLaunchKernelGGL(transpose_kernel, dim3(32 * 56), dim3(256), 0, stream,
                     Wv, Wt + (size_t)6144 * HID, HID, 2048);
  hipLaunchKernelGGL(transpose_kernel, dim3(56 * 64), dim3(256), 0, stream,
                     Wo, WtO, 4096, HID);
  hipLaunchKernelGGL(qkv_gemm8_kernel, dim3(256), dim3(512), 0, stream,
                     hsb, Wt, qb, kbuf, vtb);
  hipLaunchKernelGGL(rope_kernel, dim3(3072), dim3(256), 0, stream, qb, kbuf, tbl);
  hipLaunchKernelGGL(attn_kernel, dim3(512), dim3(256), 0, stream,
                     qb, kbuf, vtb, attnb);
  hipLaunchKernelGGL(out_gemm8_kernel, dim3(224), dim3(512), 0, stream,
                     attnb, WtO, out);
}

// Round 4
// 439.055 us; speedup vs baseline: 1.1593x; 1.1593x over previous
//
#include <hip/hip_runtime.h>
#include <stdint.h>

#define S 2048
#define HID 3584
#define NH 16
#define NKV 8
#define DH 256
#define WINDOW 1024
#define SCALE 0.0625f
#define CAP 50.0f

typedef short s16x8 __attribute__((ext_vector_type(8)));
typedef float f32x4 __attribute__((ext_vector_type(4)));

__device__ __forceinline__ short f2bf(float f) {
  union { float f; uint32_t u; } c; c.f = f;
  uint32_t u = c.u;
  uint32_t r = (u + 0x7FFFu + ((u >> 16) & 1u)) >> 16;
  return (short)r;
}
__device__ __forceinline__ float bf2f(short s) {
  union { uint32_t u; float f; } c;
  c.u = ((uint32_t)(uint16_t)s) << 16;
  return c.f;
}
__device__ __forceinline__ void gll16(const void* g, void* l) {
  __builtin_amdgcn_global_load_lds((const __attribute__((address_space(1))) void*)g,
                                   (__attribute__((address_space(3))) void*)l, 16, 0, 0);
}

// ---------------- RoPE table ----------------
__global__ void rope_table_kernel(float2* __restrict__ tbl) {
  int idx = blockIdx.x * 256 + threadIdx.x;
  int s = idx >> 7, i = idx & 127;
  float inv = __expf(-(float)i * (9.210340371976184f / 128.0f));
  float fr = (float)s * inv;
  tbl[idx] = make_float2(cosf(fr), sinf(fr));
}

// ---------------- hs fp32 -> bf16 ----------------
__global__ void conv_hs_kernel(const float* __restrict__ src, short* __restrict__ dst) {
  int gid = blockIdx.x * 256 + threadIdx.x;
  float4 a = *(const float4*)&src[(size_t)gid * 8];
  float4 b = *(const float4*)&src[(size_t)gid * 8 + 4];
  s16x8 o;
  o[0] = f2bf(a.x); o[1] = f2bf(a.y); o[2] = f2bf(a.z); o[3] = f2bf(a.w);
  o[4] = f2bf(b.x); o[5] = f2bf(b.y); o[6] = f2bf(b.z); o[7] = f2bf(b.w);
  *(s16x8*)&dst[(size_t)gid * 8] = o;
}

// ---------------- W fp32 [K][N] -> bf16 [N][K] (transpose+convert) --------
__global__ __launch_bounds__(256)
void transpose_kernel(const float* __restrict__ src, short* __restrict__ dst,
                      int K, int N)
{
  __shared__ __align__(16) short t[64][76];
  int ntn = N >> 6;
  int tn = blockIdx.x % ntn, tk = blockIdx.x / ntn;
  int tid = threadIdx.x;
  int c = tid & 63, rg = tid >> 6;
  #pragma unroll
  for (int i = 0; i < 4; ++i) {
    int r0 = i * 16 + rg * 4;
    short tmp[4];
    #pragma unroll
    for (int j = 0; j < 4; ++j)
      tmp[j] = f2bf(src[(size_t)(tk * 64 + r0 + j) * N + tn * 64 + c]);
    *(short4*)&t[c][r0] = *(short4*)tmp;
  }
  __syncthreads();
  #pragma unroll
  for (int it = 0; it < 2; ++it) {
    int flat = it * 256 + tid;
    int n = flat >> 3, kc = flat & 7;
    *(s16x8*)&dst[(size_t)(tn * 64 + n) * K + tk * 64 + kc * 8] = *(s16x8*)&t[n][kc * 8];
  }
}

// ====== 256xBN GEMM core: skewed-wave pipeline, BK=64, 512 thr, 2 bar/tile ==
// LDS XOR-swizzle col8 ^= (row&7) on both stage-source and frag-read sides.
// Within a tile: NO barriers (reads from buf cur, stage writes other buf) ->
// waves skew, LDS reads of one wave overlap MFMA of another.
template<int BN, int KS>
__device__ __forceinline__ void gemm8_core(const short* __restrict__ srcA,
                                           const short* __restrict__ srcB,
                                           int tid, int NT,
                                           f32x4 (&acc)[8][BN / 64])
{
  constexpr int NF  = BN / 64;     // n-frags per wave (4 or 2)
  constexpr int BSI = BN / 64;     // B stage instructions per tile per wave
  constexpr int WC  = BN / 4;      // per-wave cols
  __shared__ __align__(16) short Asb[2 * 16384];
  __shared__ __align__(16) short Bsb[2 * BN * 64];
  const int wv = tid >> 6, lane = tid & 63;
  const int lr = lane & 15, lk = lane >> 4;
  const int wm_id = wv >> 2, wn_id = wv & 3;
  const int r7 = lr & 7;
  const int abase = (wm_id * 128 + lr) * 64 + ((lk ^ r7) * 8);
  const int bbase = (wn_id * WC + lr) * 64 + ((lk ^ r7) * 8);

  auto stage = [&](int kt, int b) {
    const short* sa = srcA + kt * 64;
    const short* sb = srcB + kt * 64;
    short* la = Asb + b * 16384 + wv * 512;
    short* lb = Bsb + b * BN * 64 + wv * 512;
    #pragma unroll
    for (int i = 0; i < 4; ++i)
      gll16(sa + (size_t)i * 64 * KS, la + i * 4096);
    #pragma unroll
    for (int i = 0; i < BSI; ++i)
      gll16(sb + (size_t)i * 64 * KS, lb + i * 4096);
  };

  stage(0, 0);
  stage(1, 1);
  if constexpr (BN == 256) asm volatile("s_waitcnt vmcnt(8)" ::: "memory");
  else                     asm volatile("s_waitcnt vmcnt(6)" ::: "memory");
  asm volatile("s_barrier" ::: "memory");

  for (int t = 0; t < NT; ++t) {
    const int cur = t & 1;
    const short* A = Asb + cur * 16384;
    const short* B = Bsb + cur * BN * 64;
    // all B-frags once per tile (kept in regs across both m-halves)
    s16x8 bfr[NF][2];
    #pragma unroll
    for (int nf = 0; nf < NF; ++nf)
      #pragma unroll
      for (int kh = 0; kh < 2; ++kh)
        bfr[nf][kh] = *(const s16x8*)&B[(bbase + nf * 16 * 64) ^ (kh * 32)];
    #pragma unroll
    for (int mh = 0; mh < 2; ++mh) {
      s16x8 af[4][2];
      #pragma unroll
      for (int mf = 0; mf < 4; ++mf)
        #pragma unroll
        for (int kh = 0; kh < 2; ++kh)
          af[mf][kh] = *(const s16x8*)&A[(abase + (mh * 64 + mf * 16) * 64) ^ (kh * 32)];
      __builtin_amdgcn_s_setprio(1);
      #pragma unroll
      for (int mf = 0; mf < 4; ++mf)
        #pragma unroll
        for (int nf = 0; nf < NF; ++nf) {
          acc[mh * 4 + mf][nf] =
            __builtin_amdgcn_mfma_f32_16x16x32_bf16(af[mf][0], bfr[nf][0],
                                                    acc[mh * 4 + mf][nf], 0, 0, 0);
          acc[mh * 4 + mf][nf] =
            __builtin_amdgcn_mfma_f32_16x16x32_bf16(af[mf][1], bfr[nf][1],
                                                    acc[mh * 4 + mf][nf], 0, 0, 0);
        }
      __builtin_amdgcn_s_setprio(0);
    }
    // barrier #1: all waves done reading buf cur -> safe to overwrite
    asm volatile("s_barrier" ::: "memory");
    if (t + 2 < NT) {
      stage(t + 2, cur);
      if constexpr (BN == 256) asm volatile("s_waitcnt vmcnt(8)" ::: "memory");
      else                     asm volatile("s_waitcnt vmcnt(6)" ::: "memory");
      asm volatile("s_barrier" ::: "memory");   // barrier #2: buf for t+1 ready
    } else if (t + 1 < NT) {
      asm volatile("s_waitcnt vmcnt(0)" ::: "memory");
      asm volatile("s_barrier" ::: "memory");
    }
  }
}

// ---------------- Fused QKV GEMM (256^2) ----------------
__global__ __launch_bounds__(512, 2)
void qkv_gemm8_kernel(const short* __restrict__ hsb, const short* __restrict__ Wt,
                      short* __restrict__ qb, short* __restrict__ kbuf,
                      short* __restrict__ vtb)
{
  int bid = blockIdx.x;                      // 256 blocks = 8 bm x 32 bn
  int swz = (bid & 7) * 32 + (bid >> 3);
  int bm = swz >> 5, bn = swz & 31;
  int m0 = bm * 256, n0 = bn * 256;
  int tid = threadIdx.x;
  int row8 = tid >> 3;
  int colsw = ((tid & 7) ^ (row8 & 7)) * 8;
  const short* srcA = hsb + (size_t)(m0 + row8) * HID + colsw;
  const short* srcB = Wt + (size_t)(n0 + row8) * HID + colsw;
  f32x4 acc[8][4] = {};
  gemm8_core<256, HID>(srcA, srcB, tid, HID / 64, acc);

  int wv = tid >> 6, lane = tid & 63;
  int lr = lane & 15, lk = lane >> 4;
  int wm = (wv >> 2) * 128, wn = (wv & 3) * 64;
  int region = (n0 < 4096) ? 0 : ((n0 < 6144) ? 1 : 2);
  #pragma unroll
  for (int m = 0; m < 8; ++m) {
    int srow_b = m0 + wm + m * 16 + lk * 4;
    #pragma unroll
    for (int n = 0; n < 4; ++n) {
      int ncol = n0 + wn + n * 16 + lr;
      #pragma unroll
      for (int r = 0; r < 4; ++r) {
        int srow = srow_b + r;
        short bv = f2bf(acc[m][n][r]);
        if (region == 0) {
          int h = ncol >> 8, d = ncol & 255;
          qb[((size_t)h * S + srow) * DH + d] = bv;
        } else if (region == 1) {
          int c = ncol - 4096; int kv = c >> 8, d = c & 255;
          kbuf[((size_t)kv * S + srow) * DH + d] = bv;
        } else {
          int c = ncol - 6144; int kv = c >> 8, d = c & 255;
          vtb[((size_t)kv * DH + d) * S + srow] = bv;
        }
      }
    }
  }
}

// ---------------- Output GEMM (256x128) ----------------
__global__ __launch_bounds__(512, 2)
void out_gemm8_kernel(const short* __restrict__ attnb, const short* __restrict__ WtO,
                      float* __restrict__ out)
{
  int bid = blockIdx.x;                      // 224 blocks = 8 bm x 28 bn
  int swz = (bid & 7) * 28 + (bid >> 3);
  int bm = swz / 28, bn = swz % 28;
  int m0 = bm * 256, n0 = bn * 128;
  int tid = threadIdx.x;
  int row8 = tid >> 3;
  int colsw = ((tid & 7) ^ (row8 & 7)) * 8;
  const short* srcA = attnb + (size_t)(m0 + row8) * 4096 + colsw;
  const short* srcB = WtO + (size_t)(n0 + row8) * 4096 + colsw;
  f32x4 acc[8][2] = {};
  gemm8_core<128, 4096>(srcA, srcB, tid, 4096 / 64, acc);

  int wv = tid >> 6, lane = tid & 63;
  int lr = lane & 15, lk = lane >> 4;
  int wm = (wv >> 2) * 128, wn = (wv & 3) * 32;
  #pragma unroll
  for (int m = 0; m < 8; ++m) {
    int srow_b = m0 + wm + m * 16 + lk * 4;
    #pragma unroll
    for (int n = 0; n < 2; ++n) {
      int ncol = n0 + wn + n * 16 + lr;
      #pragma unroll
      for (int r = 0; r < 4; ++r)
        out[(size_t)(srow_b + r) * HID + ncol] = acc[m][n][r];
    }
  }
}

// ---------------- RoPE (NeoX, in place on q and k) ----------------
__global__ void rope_kernel(short* __restrict__ qb, short* __restrict__ kbuf,
                            const float2* __restrict__ tbl)
{
  int gid = blockIdx.x * 256 + threadIdx.x;
  int row = gid >> 4, ch = gid & 15;
  short* base = (row < NH * S) ? (qb + (size_t)row * DH)
                               : (kbuf + (size_t)(row - NH * S) * DH);
  int s = row & (S - 1);
  int i0 = ch * 8;
  s16x8 x1 = *(s16x8*)(base + i0);
  s16x8 x2 = *(s16x8*)(base + 128 + i0);
  s16x8 y1, y2;
  #pragma unroll
  for (int j = 0; j < 8; ++j) {
    float2 cs = tbl[s * 128 + i0 + j];
    float a = bf2f(x1[j]), b = bf2f(x2[j]);
    y1[j] = f2bf(a * cs.x - b * cs.y);
    y2[j] = f2bf(b * cs.x + a * cs.y);
  }
  *(s16x8*)(base + i0) = y1;
  *(s16x8*)(base + 128 + i0) = y2;
}

// ---------------- Attention (flash-style, GQA, window+causal, softcap) ----
__global__ __launch_bounds__(256)
void attn_kernel(const short* __restrict__ qb, const short* __restrict__ kbuf,
                 const short* __restrict__ vtb, short* __restrict__ attnb)
{
  __shared__ __align__(16) short Klds[64][264];
  __shared__ __align__(16) short Vlds[256][72];
  __shared__ __align__(16) short Plds[4][16][72];
  int bid = blockIdx.x;
  int h = bid >> 5, qt = bid & 31;
  int kv = h >> 1;
  int q0 = qt * 64;
  int tid = threadIdx.x, w = tid >> 6, lane = tid & 63;
  int lr = lane & 15, lk = lane >> 4;
  int qrow_base = q0 + w * 16;
  s16x8 qf[8];
  const short* qrow = qb + ((size_t)h * S + (qrow_base + lr)) * DH;
  #pragma unroll
  for (int kb = 0; kb < 8; ++kb)
    qf[kb] = *(const s16x8*)(qrow + kb * 32 + lk * 8);
  f32x4 acc_o[16] = {};
  float m_r[4], l_r[4];
  #pragma unroll
  for (int r = 0; r < 4; ++r) { m_r[r] = -1e30f; l_r[r] = 0.0f; }
  int tlo = (q0 >= WINDOW - 1) ? ((q0 - (WINDOW - 1)) >> 6) : 0;
  int thi = q0 >> 6;
  const short* kbase = kbuf + (size_t)kv * S * DH;
  const short* vbase = vtb + (size_t)kv * DH * S;
  for (int t = tlo; t <= thi; ++t) {
    int k0 = t * 64;
    __syncthreads();
    #pragma unroll
    for (int it = 0; it < 8; ++it) {
      int ch = it * 256 + tid;
      int r = ch >> 5, cg = ch & 31;
      *(s16x8*)&Klds[r][cg * 8] = *(const s16x8*)(kbase + (size_t)(k0 + r) * DH + cg * 8);
    }
    #pragma unroll
    for (int it = 0; it < 8; ++it) {
      int ch = it * 256 + tid;
      int r = ch >> 3, cg = ch & 7;
      *(s16x8*)&Vlds[r][cg * 8] = *(const s16x8*)(vbase + (size_t)r * S + k0 + cg * 8);
    }
    __syncthreads();
    f32x4 sc[4] = {};
    #pragma unroll
    for (int kb = 0; kb < 8; ++kb)
      #pragma unroll
      for (int ni = 0; ni < 4; ++ni) {
        s16x8 b = *(const s16x8*)&Klds[ni * 16 + lr][kb * 32 + lk * 8];
        sc[ni] = __builtin_amdgcn_mfma_f32_16x16x32_bf16(qf[kb], b, sc[ni], 0, 0, 0);
      }
    bool validm[4][4];
    #pragma unroll
    for (int ni = 0; ni < 4; ++ni)
      #pragma unroll
      for (int r = 0; r < 4; ++r) {
        float sv = sc[ni][r] * SCALE;
        sv = CAP * tanhf(sv * (1.0f / CAP));
        int qg = qrow_base + lk * 4 + r;
        int kg = k0 + ni * 16 + lr;
        bool valid = (kg <= qg) && (qg - kg < WINDOW);
        validm[ni][r] = valid;
        sc[ni][r] = valid ? sv : -1e30f;
      }
    float alpha[4];
    #pragma unroll
    for (int r = 0; r < 4; ++r) {
      float mx = fmaxf(fmaxf(sc[0][r], sc[1][r]), fmaxf(sc[2][r], sc[3][r]));
      #pragma unroll
      for (int off = 1; off < 16; off <<= 1)
        mx = fmaxf(mx, __shfl_xor(mx, off, 64));
      float mnew = fmaxf(m_r[r], mx);
      alpha[r] = __expf(m_r[r] - mnew);
      m_r[r] = mnew;
      float sum = 0.0f;
      #pragma unroll
      for (int ni = 0; ni < 4; ++ni) {
        float p = validm[ni][r] ? __expf(sc[ni][r] - mnew) : 0.0f;
        sc[ni][r] = p;
        sum += p;
      }
      #pragma unroll
      for (int off = 1; off < 16; off <<= 1)
        sum += __shfl_xor(sum, off, 64);
      l_r[r] = l_r[r] * alpha[r] + sum;
    }
    #pragma unroll
    for (int ni = 0; ni < 4; ++ni)
      #pragma unroll
      for (int r = 0; r < 4; ++r)
        Plds[w][lk * 4 + r][ni * 16 + lr] = f2bf(sc[ni][r]);
    __syncthreads();
    #pragma unroll
    for (int df = 0; df < 16; ++df)
      #pragma unroll
      for (int r = 0; r < 4; ++r)
        acc_o[df][r] *= alpha[r];
    s16x8 pa0 = *(const s16x8*)&Plds[w][lr][lk * 8];
    s16x8 pa1 = *(const s16x8*)&Plds[w][lr][32 + lk * 8];
    #pragma unroll
    for (int df = 0; df < 16; ++df) {
      s16x8 b0 = *(const s16x8*)&Vlds[df * 16 + lr][lk * 8];
      s16x8 b1 = *(const s16x8*)&Vlds[df * 16 + lr][32 + lk * 8];
      acc_o[df] = __builtin_amdgcn_mfma_f32_16x16x32_bf16(pa0, b0, acc_o[df], 0, 0, 0);
      acc_o[df] = __builtin_amdgcn_mfma_f32_16x16x32_bf16(pa1, b1, acc_o[df], 0, 0, 0);
    }
  }
  #pragma unroll
  for (int r = 0; r < 4; ++r) {
    int srow = qrow_base + lk * 4 + r;
    float inv = 1.0f / l_r[r];
    #pragma unroll
    for (int df = 0; df < 16; ++df)
      attnb[(size_t)srow * (NH * DH) + h * DH + df * 16 + lr] = f2bf(acc_o[df][r] * inv);
  }
}

extern "C" void kernel_launch(void* const* d_in, const int* in_sizes, int n_in,
                              void* d_out, int out_size, void* d_ws, size_t ws_size,
                              hipStream_t stream) {
  const float* hs = (const float*)d_in[0];
  const float* Wq = (const float*)d_in[2];
  const float* Wk = (const float*)d_in[3];
  const float* Wv = (const float*)d_in[4];
  const float* Wo = (const float*)d_in[5];
  float* out = (float*)d_out;
  char* ws = (char*)d_ws;
  size_t off = 0;
  float2* tbl  = (float2*)(ws + off); off += 2097152;
  short* qb    = (short*)(ws + off);  off += 16777216;           // q  [H][S][D]
  short* kbuf  = (short*)(ws + off);  off += 8388608;            // k  [KV][S][D]
  short* vtb   = (short*)(ws + off);  off += 8388608;            // vT [KV][D][S]
  short* attnb = (short*)(ws + off);  off += 16777216;           // attn [S][4096]
  short* hsb   = (short*)(ws + off);  off += 14680064;           // hs bf16
  short* Wt    = (short*)(ws + off);  off += 58720256;           // [8192][3584]
  short* WtO   = (short*)(ws + off);  off += 29360128;           // [3584][4096]

  hipLaunchKernelGGL(rope_table_kernel, dim3(1024), dim3(256), 0, stream, tbl);
  hipLaunchKernelGGL(conv_hs_kernel, dim3(3584), dim3(256), 0, stream, hs, hsb);
  hipLaunchKernelGGL(transpose_kernel, dim3(64 * 56), dim3(256), 0, stream,
                     Wq, Wt, HID, 4096);
  hipLaunchKernelGGL(transpose_kernel, dim3(32 * 56), dim3(256), 0, stream,
                     Wk, Wt + (size_t)4096 * HID, HID, 2048);
  hipLaunchKernelGGL(transpose_kernel, dim3(32 * 56), dim3(256), 0, stream,
                     Wv, Wt + (size_t)6144 * HID, HID, 2048);
  hipLaunchKernelGGL(transpose_kernel, dim3(56 * 64), dim3(256), 0, stream,
                     Wo, WtO, 4096, HID);
  hipLaunchKernelGGL(qkv_gemm8_kernel, dim3(256), dim3(512), 0, stream,
                     hsb, Wt, qb, kbuf, vtb);
  hipLaunchKernelGGL(rope_kernel, dim3(3072), dim3(256), 0, stream, qb, kbuf, tbl);
  hipLaunchKernelGGL(attn_kernel, dim3(512), dim3(256), 0, stream,
                     qb, kbuf, vtb, attnb);
  hipLaunchKernelGGL(out_gemm8_kernel, dim3(224), dim3(512), 0, stream,
                     attnb, WtO, out);
}